// Round 2
// baseline (1490.659 us; speedup 1.0000x reference)
//
#include <hip/hip_runtime.h>
#include <cstdint>

#define HEADS 4
#define C 128
#define HID 512
#define BB 2
#define HH 256
#define WW_ 256
#define SHIFT_ 4

__device__ __forceinline__ float bf2f(unsigned short u) {
    unsigned v = ((unsigned)u) << 16;
    return __uint_as_float(v);
}
__device__ __forceinline__ unsigned short f2bf(float f) {
    unsigned u = __float_as_uint(f);
    return (unsigned short)((u + 0x7fffu + ((u >> 16) & 1u)) >> 16);
}

__device__ __forceinline__ void unpack8(uint4 u, float* dst, float sc) {
    dst[0] = bf2f((unsigned short)(u.x & 0xffffu)) * sc;
    dst[1] = bf2f((unsigned short)(u.x >> 16)) * sc;
    dst[2] = bf2f((unsigned short)(u.y & 0xffffu)) * sc;
    dst[3] = bf2f((unsigned short)(u.y >> 16)) * sc;
    dst[4] = bf2f((unsigned short)(u.z & 0xffffu)) * sc;
    dst[5] = bf2f((unsigned short)(u.z >> 16)) * sc;
    dst[6] = bf2f((unsigned short)(u.w & 0xffffu)) * sc;
    dst[7] = bf2f((unsigned short)(u.w >> 16)) * sc;
}

// out[tok][o] = sum_c aT[tok][c] * w[c][o]  (w stored bf16, [c][LDW]).
// Thread handles tokens tb,tb+16,tb+32,tb+48 and outputs og..og+7.
template <int LDA, int LDW>
__device__ __forceinline__ void gemm_tile(const float* __restrict__ aT,
                                          const unsigned short* __restrict__ w,
                                          int tb, int og, float acc[4][8]) {
#pragma unroll 4
    for (int c = 0; c < 128; ++c) {
        const unsigned short* wr = w + c * LDW + og;
        ushort4 u0 = *(const ushort4*)(wr);
        ushort4 u1 = *(const ushort4*)(wr + 4);
        float wv[8];
        wv[0] = bf2f(u0.x); wv[1] = bf2f(u0.y); wv[2] = bf2f(u0.z); wv[3] = bf2f(u0.w);
        wv[4] = bf2f(u1.x); wv[5] = bf2f(u1.y); wv[6] = bf2f(u1.z); wv[7] = bf2f(u1.w);
        float a0 = aT[(tb + 0) * LDA + c];
        float a1 = aT[(tb + 16) * LDA + c];
        float a2 = aT[(tb + 32) * LDA + c];
        float a3 = aT[(tb + 48) * LDA + c];
#pragma unroll
        for (int i = 0; i < 8; ++i) {
            acc[0][i] += a0 * wv[i];
            acc[1][i] += a1 * wv[i];
            acc[2][i] += a2 * wv[i];
            acc[3][i] += a3 * wv[i];
        }
    }
}

// ------------------- kernel 1: LN(x) (pre-rolled) + Q projection --------------------
__global__ __launch_bounds__(256) void k_ln_q(const float* __restrict__ x,
                                              const float* __restrict__ g,
                                              const float* __restrict__ be,
                                              const float* __restrict__ qw,
                                              const float* __restrict__ qb,
                                              unsigned short* __restrict__ qbuf) {
    __shared__ float aT[64 * 129];
    __shared__ unsigned short wT[128 * 132];
    __shared__ float red1[256], red2[256];
    __shared__ float mbuf[64], rbuf[64];
    __shared__ float gs[128], bs[128];

    int t = threadIdx.x;
    int blk = blockIdx.x;
    int b = blk >> 10;
    int rem = blk & 1023;
    int h = rem >> 2;
    int w0 = (rem & 3) << 6;
    int hs = (h + SHIFT_) & 255;

    if (t < 128) { gs[t] = g[t]; bs[t] = be[t]; }

    int j = t & 63, p = t >> 6;
    int wsrc = (w0 + j + SHIFT_) & 255;
    float s1 = 0.f, s2 = 0.f;
#pragma unroll 8
    for (int k = 0; k < 32; ++k) {
        int c = p + 4 * k;
        float v = x[((b * C + c) * HH + hs) * WW_ + wsrc];
        aT[j * 129 + c] = v;
        s1 += v; s2 += v * v;
    }
    red1[t] = s1; red2[t] = s2;
    __syncthreads();
    if (t < 64) {
        float a = red1[t] + red1[64 + t] + red1[128 + t] + red1[192 + t];
        float q2 = red2[t] + red2[64 + t] + red2[128 + t] + red2[192 + t];
        float m = a * (1.f / 128.f);
        float var = q2 * (1.f / 128.f) - m * m;
        mbuf[t] = m; rbuf[t] = rsqrtf(var + 1e-5f);
    }
    __syncthreads();
    {
        float m = mbuf[j], r = rbuf[j];
#pragma unroll 8
        for (int k = 0; k < 32; ++k) {
            int c = p + 4 * k;
            float v = aT[j * 129 + c];
            aT[j * 129 + c] = (v - m) * r * gs[c] + bs[c];
        }
    }
    for (int s = 0; s < 64; ++s) {
        int idx = s * 256 + t;
        int o = idx >> 7, c = idx & 127;
        wT[c * 132 + o] = f2bf(qw[o * 128 + c]);
    }
    __syncthreads();

    int l = t & 63, wv = t >> 6;
    int tb = l & 15, og = wv * 32 + (l >> 4) * 8;
    float acc[4][8];
#pragma unroll
    for (int k = 0; k < 4; ++k)
#pragma unroll
        for (int i = 0; i < 8; ++i) acc[k][i] = 0.f;
    gemm_tile<129, 132>(aT, wT, tb, og, acc);

    int tokbase = (b * HH + h) * WW_ + w0;
#pragma unroll
    for (int k = 0; k < 4; ++k) {
        unsigned short o8[8];
#pragma unroll
        for (int i = 0; i < 8; ++i) o8[i] = f2bf(acc[k][i] + qb[og + i]);
        ushort4* dst = (ushort4*)&qbuf[(tokbase + tb + 16 * k) * 128 + og];
        dst[0] = make_ushort4(o8[0], o8[1], o8[2], o8[3]);
        dst[1] = make_ushort4(o8[4], o8[5], o8[6], o8[7]);
    }
}

// ------------------- kernel 2: LN(kv) (pre-rolled) + K,V projections --------------------
__global__ __launch_bounds__(256) void k_ln_kv(const float* __restrict__ kv,
                                               const float* __restrict__ g,
                                               const float* __restrict__ be,
                                               const float* __restrict__ kvw,
                                               const float* __restrict__ kvb,
                                               unsigned short* __restrict__ kbuf,
                                               unsigned short* __restrict__ vbuf) {
    __shared__ float aT[64 * 129];
    __shared__ unsigned short wT[128 * 132];
    __shared__ float red1[256], red2[256];
    __shared__ float mbuf[64], rbuf[64];
    __shared__ float gs[128], bs[128];

    int t = threadIdx.x;
    int blk = blockIdx.x;
    int b = blk >> 10;
    int rem = blk & 1023;
    int h = rem >> 2;
    int w0 = (rem & 3) << 6;
    int hs = (h + SHIFT_) & 255;

    if (t < 128) { gs[t] = g[t]; bs[t] = be[t]; }

    int j = t & 63, p = t >> 6;
    int wsrc = (w0 + j + SHIFT_) & 255;
    float s1 = 0.f, s2 = 0.f;
#pragma unroll 8
    for (int k = 0; k < 32; ++k) {
        int c = p + 4 * k;
        float v = kv[((b * C + c) * HH + hs) * WW_ + wsrc];
        aT[j * 129 + c] = v;
        s1 += v; s2 += v * v;
    }
    red1[t] = s1; red2[t] = s2;
    __syncthreads();
    if (t < 64) {
        float a = red1[t] + red1[64 + t] + red1[128 + t] + red1[192 + t];
        float q2 = red2[t] + red2[64 + t] + red2[128 + t] + red2[192 + t];
        float m = a * (1.f / 128.f);
        float var = q2 * (1.f / 128.f) - m * m;
        mbuf[t] = m; rbuf[t] = rsqrtf(var + 1e-5f);
    }
    __syncthreads();
    {
        float m = mbuf[j], r = rbuf[j];
#pragma unroll 8
        for (int k = 0; k < 32; ++k) {
            int c = p + 4 * k;
            float v = aT[j * 129 + c];
            aT[j * 129 + c] = (v - m) * r * gs[c] + bs[c];
        }
    }

    int l = t & 63, wv = t >> 6;
    int tb = l & 15, og = wv * 32 + (l >> 4) * 8;
    int tokbase = (b * HH + h) * WW_ + w0;

    for (int half = 0; half < 2; ++half) {
        __syncthreads();  // wT safe to (re)write; also covers aT normalize on first pass
        for (int s = 0; s < 64; ++s) {
            int idx = s * 256 + t;
            int o = idx >> 7, c = idx & 127;
            wT[c * 132 + o] = f2bf(kvw[(half * 128 + o) * 128 + c]);
        }
        __syncthreads();
        float acc[4][8];
#pragma unroll
        for (int k = 0; k < 4; ++k)
#pragma unroll
            for (int i = 0; i < 8; ++i) acc[k][i] = 0.f;
        gemm_tile<129, 132>(aT, wT, tb, og, acc);
        unsigned short* dbuf = half ? vbuf : kbuf;
#pragma unroll
        for (int k = 0; k < 4; ++k) {
            unsigned short o8[8];
#pragma unroll
            for (int i = 0; i < 8; ++i) o8[i] = f2bf(acc[k][i] + kvb[half * 128 + og + i]);
            ushort4* dst = (ushort4*)&dbuf[(tokbase + tb + 16 * k) * 128 + og];
            dst[0] = make_ushort4(o8[0], o8[1], o8[2], o8[3]);
            dst[1] = make_ushort4(o8[4], o8[5], o8[6], o8[7]);
        }
    }
}

// ------------------- kernel 3: windowed attention + proj --------------------
__global__ __launch_bounds__(256) void k_attn(const unsigned short* __restrict__ qbuf,
                                              const unsigned short* __restrict__ kbuf,
                                              const unsigned short* __restrict__ vbuf,
                                              const float* __restrict__ rpb,
                                              const float* __restrict__ pw,
                                              const float* __restrict__ pb,
                                              unsigned short* __restrict__ pbuf) {
    __shared__ float qt[64 * 132];
    __shared__ float kt[64 * 132];
    __shared__ float vt[64 * 132];
    __shared__ float rp[900];

    int t = threadIdx.x;
    int b = blockIdx.x >> 10;
    int wl = blockIdx.x & 1023;
    int wh = wl >> 5, wwid = wl & 31;

    for (int i = t; i < 900; i += 256) rp[i] = rpb[i];

    {
        int j = t >> 2, qd = t & 3;
        int r = j >> 3, cc = j & 7;
        int gtok = (b * HH + wh * 8 + r) * WW_ + wwid * 8 + cc;
        const uint4* qs = (const uint4*)&qbuf[gtok * 128 + qd * 32];
        const uint4* ks = (const uint4*)&kbuf[gtok * 128 + qd * 32];
        const uint4* vs = (const uint4*)&vbuf[gtok * 128 + qd * 32];
#pragma unroll
        for (int q4 = 0; q4 < 4; ++q4) {
            unpack8(qs[q4], &qt[j * 132 + qd * 32 + q4 * 8], 0.17677669529663689f);
            unpack8(ks[q4], &kt[j * 132 + qd * 32 + q4 * 8], 1.f);
            unpack8(vs[q4], &vt[j * 132 + qd * 32 + q4 * 8], 1.f);
        }
    }
    __syncthreads();

    int head = t >> 6, l = t & 63;
    float qreg[32];
#pragma unroll
    for (int i = 0; i < 32; ++i) qreg[i] = qt[l * 132 + head * 32 + i];

    int qr = l >> 3, qc = l & 7;
    int hq = wh * 8 + qr, wq = wwid * 8 + qc;
    int regq = (hq < 248 ? 0 : (hq < 252 ? 1 : 2)) * 3 + (wq < 248 ? 0 : (wq < 252 ? 1 : 2));

    float sarr[64];
#pragma unroll
    for (int k = 0; k < 64; ++k) {
        const float4* kr = (const float4*)&kt[k * 132 + head * 32];
        float s = 0.f;
#pragma unroll
        for (int i = 0; i < 8; ++i) {
            float4 k4 = kr[i];
            s += qreg[4 * i] * k4.x + qreg[4 * i + 1] * k4.y + qreg[4 * i + 2] * k4.z +
                 qreg[4 * i + 3] * k4.w;
        }
        int krr = k >> 3, kc = k & 7;
        int hk = wh * 8 + krr, wk = wwid * 8 + kc;
        int regk = (hk < 248 ? 0 : (hk < 252 ? 1 : 2)) * 3 + (wk < 248 ? 0 : (wk < 252 ? 1 : 2));
        s += rp[((qr - krr + 7) * 15 + (qc - kc + 7)) * 4 + head];
        if (regk != regq) s -= 100.f;
        sarr[k] = s;
    }
    float m = -1e30f;
#pragma unroll
    for (int k = 0; k < 64; ++k) m = fmaxf(m, sarr[k]);
    float e = 0.f;
#pragma unroll
    for (int k = 0; k < 64; ++k) {
        float ex = __expf(sarr[k] - m);
        sarr[k] = ex;
        e += ex;
    }
    float inv = 1.f / e;
    float outp[32];
#pragma unroll
    for (int i = 0; i < 32; ++i) outp[i] = 0.f;
#pragma unroll
    for (int k = 0; k < 64; ++k) {
        float pk = sarr[k];
        const float4* vr = (const float4*)&vt[k * 132 + head * 32];
#pragma unroll
        for (int i = 0; i < 8; ++i) {
            float4 v4 = vr[i];
            outp[4 * i] += pk * v4.x;
            outp[4 * i + 1] += pk * v4.y;
            outp[4 * i + 2] += pk * v4.z;
            outp[4 * i + 3] += pk * v4.w;
        }
    }
    __syncthreads();  // everyone done reading qt/kt/vt

#pragma unroll
    for (int i = 0; i < 32; ++i) qt[l * 132 + head * 32 + i] = outp[i] * inv;

    unsigned short* wT = (unsigned short*)kt;  // 128*132 shorts == 64*132 floats
    for (int s = 0; s < 64; ++s) {
        int idx = s * 256 + t;
        int o = idx >> 7, c = idx & 127;
        wT[c * 132 + o] = f2bf(pw[o * 128 + c]);
    }
    __syncthreads();

    int tb = l & 15, og = head * 32 + (l >> 4) * 8;
    float acc[4][8];
#pragma unroll
    for (int k = 0; k < 4; ++k)
#pragma unroll
        for (int i = 0; i < 8; ++i) acc[k][i] = 0.f;
    gemm_tile<132, 132>(qt, wT, tb, og, acc);

#pragma unroll
    for (int k = 0; k < 4; ++k) {
        int tok = tb + 16 * k;
        int r = tok >> 3, cc = tok & 7;
        int hu = (wh * 8 + r + SHIFT_) & 255;
        int wu = (wwid * 8 + cc + SHIFT_) & 255;
        unsigned short o8[8];
#pragma unroll
        for (int i = 0; i < 8; ++i) o8[i] = f2bf(acc[k][i] + pb[og + i]);
        ushort4* dst = (ushort4*)&pbuf[((b * HH + hu) * WW_ + wu) * 128 + og];
        dst[0] = make_ushort4(o8[0], o8[1], o8[2], o8[3]);
        dst[1] = make_ushort4(o8[4], o8[5], o8[6], o8[7]);
    }
}

// ------------------- kernel 4: residual + LN2 + MLP + residual --------------------
__global__ __launch_bounds__(256) void k_mlp(const float* __restrict__ x,
                                             const unsigned short* __restrict__ pbuf,
                                             const float* __restrict__ g2,
                                             const float* __restrict__ b2,
                                             const float* __restrict__ fc1w,
                                             const float* __restrict__ fc1b,
                                             const float* __restrict__ fc2w,
                                             const float* __restrict__ fc2b,
                                             float* __restrict__ out) {
    __shared__ float xo[64 * 129];
    __shared__ float x2[64 * 129];
    __shared__ float h1[64 * 129];
    __shared__ unsigned short wT[128 * 132];
    __shared__ float red1[256], red2[256];
    __shared__ float mbuf[64], rbuf[64];
    __shared__ float gs[128], bs[128];

    int t = threadIdx.x;
    int blk = blockIdx.x;
    int b = blk >> 10;
    int rem = blk & 1023;
    int h = rem >> 2;
    int w0 = (rem & 3) << 6;
    int tokbase = (b * HH + h) * WW_ + w0;

    if (t < 128) { gs[t] = g2[t]; bs[t] = b2[t]; }

    // phase A: coalesced pbuf load (bf16 rows)
    for (int s = 0; s < 4; ++s) {
        int flat = s * 256 + t;
        int j = flat >> 4, c8 = flat & 15;
        uint4 u = ((const uint4*)&pbuf[(tokbase + j) * 128])[c8];
        unpack8(u, &xo[j * 129 + c8 * 8], 1.f);
    }
    __syncthreads();

    int j = t & 63, p = t >> 6;
    float s1 = 0.f, s2 = 0.f;
#pragma unroll 8
    for (int k = 0; k < 32; ++k) {
        int c = p + 4 * k;
        float v = xo[j * 129 + c] + x[((b * C + c) * HH + h) * WW_ + w0 + j];
        xo[j * 129 + c] = v;
        s1 += v; s2 += v * v;
    }
    red1[t] = s1; red2[t] = s2;
    __syncthreads();
    if (t < 64) {
        float a = red1[t] + red1[64 + t] + red1[128 + t] + red1[192 + t];
        float q2 = red2[t] + red2[64 + t] + red2[128 + t] + red2[192 + t];
        float m = a * (1.f / 128.f);
        float var = q2 * (1.f / 128.f) - m * m;
        mbuf[t] = m; rbuf[t] = rsqrtf(var + 1e-5f);
    }
    __syncthreads();
    {
        float m = mbuf[j], r = rbuf[j];
#pragma unroll 8
        for (int k = 0; k < 32; ++k) {
            int c = p + 4 * k;
            x2[j * 129 + c] = (xo[j * 129 + c] - m) * r * gs[c] + bs[c];
        }
    }

    int l = t & 63, wv = t >> 6;
    int tb = l & 15, og = wv * 32 + (l >> 4) * 8;
    float h2[4][8];
#pragma unroll
    for (int k = 0; k < 4; ++k)
#pragma unroll
        for (int i = 0; i < 8; ++i) h2[k][i] = 0.f;

    for (int ch = 0; ch < 4; ++ch) {
        __syncthreads();  // wT free (prev gemm2 done); covers x2 writes on first pass
        for (int s = 0; s < 64; ++s) {
            int idx = s * 256 + t;
            int o = idx >> 7, c = idx & 127;
            wT[c * 132 + o] = f2bf(fc1w[(ch * 128 + o) * 128 + c]);
        }
        __syncthreads();
        float a1[4][8];
#pragma unroll
        for (int k = 0; k < 4; ++k)
#pragma unroll
            for (int i = 0; i < 8; ++i) a1[k][i] = 0.f;
        gemm_tile<129, 132>(x2, wT, tb, og, a1);
#pragma unroll
        for (int k = 0; k < 4; ++k)
#pragma unroll
            for (int i = 0; i < 8; ++i) {
                float v = a1[k][i] + fc1b[ch * 128 + og + i];
                v = 0.5f * v * (1.f + erff(v * 0.70710678118654752f));
                h1[(tb + 16 * k) * 129 + og + i] = v;
            }
        __syncthreads();
        for (int s = 0; s < 64; ++s) {
            int idx = s * 256 + t;
            int o = idx >> 7, hh2 = idx & 127;
            wT[hh2 * 132 + o] = f2bf(fc2w[o * 512 + ch * 128 + hh2]);
        }
        __syncthreads();
        gemm_tile<129, 132>(h1, wT, tb, og, h2);
    }

#pragma unroll
    for (int k = 0; k < 4; ++k)
#pragma unroll
        for (int i = 0; i < 8; ++i) {
            float val = h2[k][i] + fc2b[og + i] + xo[(tb + 16 * k) * 129 + og + i];
            out[((b * C + og + i) * HH + h) * WW_ + w0 + tb + 16 * k] = val;
        }
}

extern "C" void kernel_launch(void* const* d_in, const int* in_sizes, int n_in,
                              void* d_out, int out_size, void* d_ws, size_t ws_size,
                              hipStream_t stream) {
    const float* x    = (const float*)d_in[0];
    const float* kv   = (const float*)d_in[1];
    const float* n1g  = (const float*)d_in[2];
    const float* n1b  = (const float*)d_in[3];
    const float* qw   = (const float*)d_in[4];
    const float* qb   = (const float*)d_in[5];
    const float* kvw  = (const float*)d_in[6];
    const float* kvb  = (const float*)d_in[7];
    const float* rpb  = (const float*)d_in[8];
    const float* pw   = (const float*)d_in[9];
    const float* pb   = (const float*)d_in[10];
    const float* n2g  = (const float*)d_in[11];
    const float* n2b  = (const float*)d_in[12];
    const float* fc1w = (const float*)d_in[13];
    const float* fc1b = (const float*)d_in[14];
    const float* fc2w = (const float*)d_in[15];
    const float* fc2b = (const float*)d_in[16];
    float* out = (float*)d_out;

    char* ws = (char*)d_ws;
    unsigned short* qbuf = (unsigned short*)(ws);                 // 33,554,432 B
    unsigned short* kbuf = (unsigned short*)(ws + 33554432);      // 33,554,432 B
    unsigned short* vbuf = (unsigned short*)(ws + 67108864);      // 33,554,432 B
    unsigned short* pbuf = (unsigned short*)(ws + 100663296);     // 33,554,432 B

    dim3 blkd(256);
    k_ln_q<<<dim3(2048), blkd, 0, stream>>>(x, n1g, n1b, qw, qb, qbuf);
    k_ln_kv<<<dim3(2048), blkd, 0, stream>>>(kv, n1g, n1b, kvw, kvb, kbuf, vbuf);
    k_attn<<<dim3(2048), blkd, 0, stream>>>(qbuf, kbuf, vbuf, rpb, pw, pb, pbuf);
    k_mlp<<<dim3(2048), blkd, 0, stream>>>(x, pbuf, n2g, n2b, fc1w, fc1b, fc2w, fc2b, out);
}

// Round 3
// 780.214 us; speedup vs baseline: 1.9106x; 1.9106x over previous
//
#include <hip/hip_runtime.h>
#include <cstdint>

#define HEADS 4
#define C 128
#define HID 512
#define BB 2
#define HH 256
#define WW_ 256
#define SHIFT_ 4

typedef short v8s __attribute__((ext_vector_type(8)));
typedef float v4f __attribute__((ext_vector_type(4)));

__device__ __forceinline__ float bf2f(unsigned short u) {
    unsigned v = ((unsigned)u) << 16;
    return __uint_as_float(v);
}
__device__ __forceinline__ unsigned short f2bf(float f) {
    unsigned u = __float_as_uint(f);
    return (unsigned short)((u + 0x7fffu + ((u >> 16) & 1u)) >> 16);
}

__device__ __forceinline__ void unpack8(uint4 u, float* dst, float sc) {
    dst[0] = bf2f((unsigned short)(u.x & 0xffffu)) * sc;
    dst[1] = bf2f((unsigned short)(u.x >> 16)) * sc;
    dst[2] = bf2f((unsigned short)(u.y & 0xffffu)) * sc;
    dst[3] = bf2f((unsigned short)(u.y >> 16)) * sc;
    dst[4] = bf2f((unsigned short)(u.z & 0xffffu)) * sc;
    dst[5] = bf2f((unsigned short)(u.z >> 16)) * sc;
    dst[6] = bf2f((unsigned short)(u.w & 0xffffu)) * sc;
    dst[7] = bf2f((unsigned short)(u.w >> 16)) * sc;
}

// out[tok][o] = sum_c aT[tok][c] * w[c][o]  (w stored bf16, [c][LDW]).
template <int LDA, int LDW>
__device__ __forceinline__ void gemm_tile(const float* __restrict__ aT,
                                          const unsigned short* __restrict__ w,
                                          int tb, int og, float acc[4][8]) {
#pragma unroll 4
    for (int c = 0; c < 128; ++c) {
        const unsigned short* wr = w + c * LDW + og;
        ushort4 u0 = *(const ushort4*)(wr);
        ushort4 u1 = *(const ushort4*)(wr + 4);
        float wv[8];
        wv[0] = bf2f(u0.x); wv[1] = bf2f(u0.y); wv[2] = bf2f(u0.z); wv[3] = bf2f(u0.w);
        wv[4] = bf2f(u1.x); wv[5] = bf2f(u1.y); wv[6] = bf2f(u1.z); wv[7] = bf2f(u1.w);
        float a0 = aT[(tb + 0) * LDA + c];
        float a1 = aT[(tb + 16) * LDA + c];
        float a2 = aT[(tb + 32) * LDA + c];
        float a3 = aT[(tb + 48) * LDA + c];
#pragma unroll
        for (int i = 0; i < 8; ++i) {
            acc[0][i] += a0 * wv[i];
            acc[1][i] += a1 * wv[i];
            acc[2][i] += a2 * wv[i];
            acc[3][i] += a3 * wv[i];
        }
    }
}

// ------------------- kernel 1: LN(x) (pre-rolled) + Q projection --------------------
__global__ __launch_bounds__(256) void k_ln_q(const float* __restrict__ x,
                                              const float* __restrict__ g,
                                              const float* __restrict__ be,
                                              const float* __restrict__ qw,
                                              const float* __restrict__ qb,
                                              unsigned short* __restrict__ qbuf) {
    __shared__ float aT[64 * 129];
    __shared__ unsigned short wT[128 * 132];
    __shared__ float red1[256], red2[256];
    __shared__ float mbuf[64], rbuf[64];
    __shared__ float gs[128], bs[128];

    int t = threadIdx.x;
    int blk = blockIdx.x;
    int b = blk >> 10;
    int rem = blk & 1023;
    int h = rem >> 2;
    int w0 = (rem & 3) << 6;
    int hs = (h + SHIFT_) & 255;

    if (t < 128) { gs[t] = g[t]; bs[t] = be[t]; }

    int j = t & 63, p = t >> 6;
    int wsrc = (w0 + j + SHIFT_) & 255;
    float s1 = 0.f, s2 = 0.f;
#pragma unroll 8
    for (int k = 0; k < 32; ++k) {
        int c = p + 4 * k;
        float v = x[((b * C + c) * HH + hs) * WW_ + wsrc];
        aT[j * 129 + c] = v;
        s1 += v; s2 += v * v;
    }
    red1[t] = s1; red2[t] = s2;
    __syncthreads();
    if (t < 64) {
        float a = red1[t] + red1[64 + t] + red1[128 + t] + red1[192 + t];
        float q2 = red2[t] + red2[64 + t] + red2[128 + t] + red2[192 + t];
        float m = a * (1.f / 128.f);
        float var = q2 * (1.f / 128.f) - m * m;
        mbuf[t] = m; rbuf[t] = rsqrtf(var + 1e-5f);
    }
    __syncthreads();
    {
        float m = mbuf[j], r = rbuf[j];
#pragma unroll 8
        for (int k = 0; k < 32; ++k) {
            int c = p + 4 * k;
            float v = aT[j * 129 + c];
            aT[j * 129 + c] = (v - m) * r * gs[c] + bs[c];
        }
    }
    for (int s = 0; s < 64; ++s) {
        int idx = s * 256 + t;
        int o = idx >> 7, c = idx & 127;
        wT[c * 132 + o] = f2bf(qw[o * 128 + c]);
    }
    __syncthreads();

    int l = t & 63, wv = t >> 6;
    int tb = l & 15, og = wv * 32 + (l >> 4) * 8;
    float acc[4][8];
#pragma unroll
    for (int k = 0; k < 4; ++k)
#pragma unroll
        for (int i = 0; i < 8; ++i) acc[k][i] = 0.f;
    gemm_tile<129, 132>(aT, wT, tb, og, acc);

    int tokbase = (b * HH + h) * WW_ + w0;
#pragma unroll
    for (int k = 0; k < 4; ++k) {
        unsigned short o8[8];
#pragma unroll
        for (int i = 0; i < 8; ++i) o8[i] = f2bf(acc[k][i] + qb[og + i]);
        ushort4* dst = (ushort4*)&qbuf[(tokbase + tb + 16 * k) * 128 + og];
        dst[0] = make_ushort4(o8[0], o8[1], o8[2], o8[3]);
        dst[1] = make_ushort4(o8[4], o8[5], o8[6], o8[7]);
    }
}

// ------------------- kernel 2: LN(kv) (pre-rolled) + K,V projections --------------------
__global__ __launch_bounds__(256) void k_ln_kv(const float* __restrict__ kv,
                                               const float* __restrict__ g,
                                               const float* __restrict__ be,
                                               const float* __restrict__ kvw,
                                               const float* __restrict__ kvb,
                                               unsigned short* __restrict__ kbuf,
                                               unsigned short* __restrict__ vbuf) {
    __shared__ float aT[64 * 129];
    __shared__ unsigned short wT[128 * 132];
    __shared__ float red1[256], red2[256];
    __shared__ float mbuf[64], rbuf[64];
    __shared__ float gs[128], bs[128];

    int t = threadIdx.x;
    int blk = blockIdx.x;
    int b = blk >> 10;
    int rem = blk & 1023;
    int h = rem >> 2;
    int w0 = (rem & 3) << 6;
    int hs = (h + SHIFT_) & 255;

    if (t < 128) { gs[t] = g[t]; bs[t] = be[t]; }

    int j = t & 63, p = t >> 6;
    int wsrc = (w0 + j + SHIFT_) & 255;
    float s1 = 0.f, s2 = 0.f;
#pragma unroll 8
    for (int k = 0; k < 32; ++k) {
        int c = p + 4 * k;
        float v = kv[((b * C + c) * HH + hs) * WW_ + wsrc];
        aT[j * 129 + c] = v;
        s1 += v; s2 += v * v;
    }
    red1[t] = s1; red2[t] = s2;
    __syncthreads();
    if (t < 64) {
        float a = red1[t] + red1[64 + t] + red1[128 + t] + red1[192 + t];
        float q2 = red2[t] + red2[64 + t] + red2[128 + t] + red2[192 + t];
        float m = a * (1.f / 128.f);
        float var = q2 * (1.f / 128.f) - m * m;
        mbuf[t] = m; rbuf[t] = rsqrtf(var + 1e-5f);
    }
    __syncthreads();
    {
        float m = mbuf[j], r = rbuf[j];
#pragma unroll 8
        for (int k = 0; k < 32; ++k) {
            int c = p + 4 * k;
            float v = aT[j * 129 + c];
            aT[j * 129 + c] = (v - m) * r * gs[c] + bs[c];
        }
    }

    int l = t & 63, wv = t >> 6;
    int tb = l & 15, og = wv * 32 + (l >> 4) * 8;
    int tokbase = (b * HH + h) * WW_ + w0;

    for (int half = 0; half < 2; ++half) {
        __syncthreads();
        for (int s = 0; s < 64; ++s) {
            int idx = s * 256 + t;
            int o = idx >> 7, c = idx & 127;
            wT[c * 132 + o] = f2bf(kvw[(half * 128 + o) * 128 + c]);
        }
        __syncthreads();
        float acc[4][8];
#pragma unroll
        for (int k = 0; k < 4; ++k)
#pragma unroll
            for (int i = 0; i < 8; ++i) acc[k][i] = 0.f;
        gemm_tile<129, 132>(aT, wT, tb, og, acc);
        unsigned short* dbuf = half ? vbuf : kbuf;
#pragma unroll
        for (int k = 0; k < 4; ++k) {
            unsigned short o8[8];
#pragma unroll
            for (int i = 0; i < 8; ++i) o8[i] = f2bf(acc[k][i] + kvb[half * 128 + og + i]);
            ushort4* dst = (ushort4*)&dbuf[(tokbase + tb + 16 * k) * 128 + og];
            dst[0] = make_ushort4(o8[0], o8[1], o8[2], o8[3]);
            dst[1] = make_ushort4(o8[4], o8[5], o8[6], o8[7]);
        }
    }
}

// ------------------- kernel 3: windowed attention + proj --------------------
__global__ __launch_bounds__(256) void k_attn(const unsigned short* __restrict__ qbuf,
                                              const unsigned short* __restrict__ kbuf,
                                              const unsigned short* __restrict__ vbuf,
                                              const float* __restrict__ rpb,
                                              const float* __restrict__ pw,
                                              const float* __restrict__ pb,
                                              unsigned short* __restrict__ pbuf) {
    __shared__ float qt[64 * 132];
    __shared__ float kt[64 * 132];
    __shared__ float vt[64 * 132];
    __shared__ float rp[900];

    int t = threadIdx.x;
    int b = blockIdx.x >> 10;
    int wl = blockIdx.x & 1023;
    int wh = wl >> 5, wwid = wl & 31;

    for (int i = t; i < 900; i += 256) rp[i] = rpb[i];

    {
        int j = t >> 2, qd = t & 3;
        int r = j >> 3, cc = j & 7;
        int gtok = (b * HH + wh * 8 + r) * WW_ + wwid * 8 + cc;
        const uint4* qs = (const uint4*)&qbuf[gtok * 128 + qd * 32];
        const uint4* ks = (const uint4*)&kbuf[gtok * 128 + qd * 32];
        const uint4* vs = (const uint4*)&vbuf[gtok * 128 + qd * 32];
#pragma unroll
        for (int q4 = 0; q4 < 4; ++q4) {
            unpack8(qs[q4], &qt[j * 132 + qd * 32 + q4 * 8], 0.17677669529663689f);
            unpack8(ks[q4], &kt[j * 132 + qd * 32 + q4 * 8], 1.f);
            unpack8(vs[q4], &vt[j * 132 + qd * 32 + q4 * 8], 1.f);
        }
    }
    __syncthreads();

    int head = t >> 6, l = t & 63;
    float qreg[32];
#pragma unroll
    for (int i = 0; i < 32; ++i) qreg[i] = qt[l * 132 + head * 32 + i];

    int qr = l >> 3, qc = l & 7;
    int hq = wh * 8 + qr, wq = wwid * 8 + qc;
    int regq = (hq < 248 ? 0 : (hq < 252 ? 1 : 2)) * 3 + (wq < 248 ? 0 : (wq < 252 ? 1 : 2));

    float sarr[64];
#pragma unroll
    for (int k = 0; k < 64; ++k) {
        const float4* kr = (const float4*)&kt[k * 132 + head * 32];
        float s = 0.f;
#pragma unroll
        for (int i = 0; i < 8; ++i) {
            float4 k4 = kr[i];
            s += qreg[4 * i] * k4.x + qreg[4 * i + 1] * k4.y + qreg[4 * i + 2] * k4.z +
                 qreg[4 * i + 3] * k4.w;
        }
        int krr = k >> 3, kc = k & 7;
        int hk = wh * 8 + krr, wk = wwid * 8 + kc;
        int regk = (hk < 248 ? 0 : (hk < 252 ? 1 : 2)) * 3 + (wk < 248 ? 0 : (wk < 252 ? 1 : 2));
        s += rp[((qr - krr + 7) * 15 + (qc - kc + 7)) * 4 + head];
        if (regk != regq) s -= 100.f;
        sarr[k] = s;
    }
    float m = -1e30f;
#pragma unroll
    for (int k = 0; k < 64; ++k) m = fmaxf(m, sarr[k]);
    float e = 0.f;
#pragma unroll
    for (int k = 0; k < 64; ++k) {
        float ex = __expf(sarr[k] - m);
        sarr[k] = ex;
        e += ex;
    }
    float inv = 1.f / e;
    float outp[32];
#pragma unroll
    for (int i = 0; i < 32; ++i) outp[i] = 0.f;
#pragma unroll
    for (int k = 0; k < 64; ++k) {
        float pk = sarr[k];
        const float4* vr = (const float4*)&vt[k * 132 + head * 32];
#pragma unroll
        for (int i = 0; i < 8; ++i) {
            float4 v4 = vr[i];
            outp[4 * i] += pk * v4.x;
            outp[4 * i + 1] += pk * v4.y;
            outp[4 * i + 2] += pk * v4.z;
            outp[4 * i + 3] += pk * v4.w;
        }
    }
    __syncthreads();

#pragma unroll
    for (int i = 0; i < 32; ++i) qt[l * 132 + head * 32 + i] = outp[i] * inv;

    unsigned short* wT = (unsigned short*)kt;
    for (int s = 0; s < 64; ++s) {
        int idx = s * 256 + t;
        int o = idx >> 7, c = idx & 127;
        wT[c * 132 + o] = f2bf(pw[o * 128 + c]);
    }
    __syncthreads();

    int tb = l & 15, og = head * 32 + (l >> 4) * 8;
    float acc[4][8];
#pragma unroll
    for (int k = 0; k < 4; ++k)
#pragma unroll
        for (int i = 0; i < 8; ++i) acc[k][i] = 0.f;
    gemm_tile<132, 132>(qt, wT, tb, og, acc);

#pragma unroll
    for (int k = 0; k < 4; ++k) {
        int tok = tb + 16 * k;
        int r = tok >> 3, cc = tok & 7;
        int hu = (wh * 8 + r + SHIFT_) & 255;
        int wu = (wwid * 8 + cc + SHIFT_) & 255;
        unsigned short o8[8];
#pragma unroll
        for (int i = 0; i < 8; ++i) o8[i] = f2bf(acc[k][i] + pb[og + i]);
        ushort4* dst = (ushort4*)&pbuf[((b * HH + hu) * WW_ + wu) * 128 + og];
        dst[0] = make_ushort4(o8[0], o8[1], o8[2], o8[3]);
        dst[1] = make_ushort4(o8[4], o8[5], o8[6], o8[7]);
    }
}

// ------------------- kernel 3.5: pack fc1w/fc2w into frag-linear bf16 --------------------
// W1p frag order: frag = nt*4 + kt   (nt 0..31 over HID, kt 0..3 over C)
//   elem: lane l, i -> fc1w[(nt*16 + (l&15)) * 128 + kt*32 + (l>>4)*8 + i]
// W2p frag order: frag = nt*16 + ktg (nt 0..7 over C, ktg 0..15 over HID)
//   elem: lane l, i -> fc2w[(nt*16 + (l&15)) * 512 + ktg*32 + (l>>4)*8 + i]
__global__ __launch_bounds__(256) void k_prep(const float* __restrict__ fc1w,
                                              const float* __restrict__ fc2w,
                                              unsigned short* __restrict__ W1p,
                                              unsigned short* __restrict__ W2p) {
    int tid = blockIdx.x * 256 + threadIdx.x;  // 0..16383
    int half = tid >> 13;
    int lf = tid & 8191;
    int l = lf & 63, frag = lf >> 6;
    int lm = l & 15, lk = l >> 4;
    if (half == 0) {
        int nt = frag >> 2, kt = frag & 3;
        const float* src = &fc1w[(nt * 16 + lm) * 128 + kt * 32 + lk * 8];
        unsigned short* dst = &W1p[lf * 8];
#pragma unroll
        for (int i = 0; i < 8; ++i) dst[i] = f2bf(src[i]);
    } else {
        int nt = frag >> 4, ktg = frag & 15;
        const float* src = &fc2w[(nt * 16 + lm) * 512 + ktg * 32 + lk * 8];
        unsigned short* dst = &W2p[lf * 8];
#pragma unroll
        for (int i = 0; i < 8; ++i) dst[i] = f2bf(src[i]);
    }
}

// ------------------- kernel 4: residual + LN2 + MFMA MLP + residual --------------------
__global__ __launch_bounds__(256, 2) void k_mlp2(const float* __restrict__ x,
                                                 const unsigned short* __restrict__ pbuf,
                                                 const float* __restrict__ g2,
                                                 const float* __restrict__ b2,
                                                 const float* __restrict__ fc1b,
                                                 const float* __restrict__ fc2b,
                                                 const unsigned short* __restrict__ W1p,
                                                 const unsigned short* __restrict__ W2p,
                                                 float* __restrict__ out) {
    __shared__ __align__(16) float xos[64 * 132];           // fp32 residual
    __shared__ __align__(16) unsigned short x2s[64 * 136];  // bf16 LN2 out (A of GEMM1)
    __shared__ __align__(16) unsigned short h1s[64 * 136];  // bf16 gelu out (A of GEMM2)
    __shared__ float red1[256], red2[256];
    __shared__ float mbuf[64], rbuf[64];
    __shared__ float gs[128], bs[128];

    int t = threadIdx.x;
    int blk = blockIdx.x;
    int b = blk >> 10;
    int rem = blk & 1023;
    int h = rem >> 2;
    int w0 = (rem & 3) << 6;
    int tokbase = (b * HH + h) * WW_ + w0;

    if (t < 128) { gs[t] = g2[t]; bs[t] = b2[t]; }

    // bf16 pbuf rows -> xos fp32
    for (int s = 0; s < 4; ++s) {
        int flat = s * 256 + t;
        int j = flat >> 4, c8 = flat & 15;
        uint4 u = ((const uint4*)&pbuf[(tokbase + j) * 128])[c8];
        unpack8(u, &xos[j * 132 + c8 * 8], 1.f);
    }
    __syncthreads();

    int j = t & 63, p = t >> 6;
    float s1 = 0.f, s2 = 0.f;
#pragma unroll 8
    for (int k = 0; k < 32; ++k) {
        int c = p + 4 * k;
        float v = xos[j * 132 + c] + x[((b * C + c) * HH + h) * WW_ + w0 + j];
        xos[j * 132 + c] = v;
        s1 += v; s2 += v * v;
    }
    red1[t] = s1; red2[t] = s2;
    __syncthreads();
    if (t < 64) {
        float a = red1[t] + red1[64 + t] + red1[128 + t] + red1[192 + t];
        float q2 = red2[t] + red2[64 + t] + red2[128 + t] + red2[192 + t];
        float m = a * (1.f / 128.f);
        float var = q2 * (1.f / 128.f) - m * m;
        mbuf[t] = m; rbuf[t] = rsqrtf(var + 1e-5f);
    }
    __syncthreads();
    {
        float m = mbuf[j], r = rbuf[j];
#pragma unroll 8
        for (int k = 0; k < 32; ++k) {
            int c = p + 4 * k;
            x2s[j * 136 + c] = f2bf((xos[j * 132 + c] - m) * r * gs[c] + bs[c]);
        }
    }
    __syncthreads();  // x2s ready for all waves

    int l = t & 63, w = t >> 6;
    int mw = (w >> 1) * 32;  // wave M offset (tokens)
    int nw = (w & 1) * 64;   // wave N offset
    int lm = l & 15, lk = l >> 4;

    v4f acc2[2][4];
#pragma unroll
    for (int mt = 0; mt < 2; ++mt)
#pragma unroll
        for (int nt = 0; nt < 4; ++nt) acc2[mt][nt] = (v4f){0.f, 0.f, 0.f, 0.f};

    for (int ch = 0; ch < 4; ++ch) {
        // B fragments straight from L2-resident packed weights
        v8s B1[4][4], B2[4][4];
#pragma unroll
        for (int nt = 0; nt < 4; ++nt)
#pragma unroll
            for (int kt = 0; kt < 4; ++kt)
                B1[nt][kt] = *(const v8s*)&W1p[(((ch * 8 + (w & 1) * 4 + nt) * 4 + kt) * 64 + l) * 8];
#pragma unroll
        for (int nt = 0; nt < 4; ++nt)
#pragma unroll
            for (int kt = 0; kt < 4; ++kt)
                B2[nt][kt] = *(const v8s*)&W2p[((((w & 1) * 4 + nt) * 16 + ch * 4 + kt) * 64 + l) * 8];

        // GEMM1: x2 @ fc1w.T (chunk of 128 hidden)
        v4f acc1[2][4];
#pragma unroll
        for (int mt = 0; mt < 2; ++mt)
#pragma unroll
            for (int nt = 0; nt < 4; ++nt) acc1[mt][nt] = (v4f){0.f, 0.f, 0.f, 0.f};
#pragma unroll
        for (int kt = 0; kt < 4; ++kt) {
            v8s A0 = *(const v8s*)&x2s[(mw + lm) * 136 + kt * 32 + lk * 8];
            v8s A1 = *(const v8s*)&x2s[(mw + 16 + lm) * 136 + kt * 32 + lk * 8];
#pragma unroll
            for (int nt = 0; nt < 4; ++nt) {
                acc1[0][nt] = __builtin_amdgcn_mfma_f32_16x16x32_bf16(A0, B1[nt][kt], acc1[0][nt], 0, 0, 0);
                acc1[1][nt] = __builtin_amdgcn_mfma_f32_16x16x32_bf16(A1, B1[nt][kt], acc1[1][nt], 0, 0, 0);
            }
        }
        __syncthreads();  // all waves done reading h1s from previous chunk
        // bias + exact GELU -> h1s (A-layout for GEMM2)
#pragma unroll
        for (int mt = 0; mt < 2; ++mt)
#pragma unroll
            for (int nt = 0; nt < 4; ++nt) {
                float bia = fc1b[ch * 128 + nw + nt * 16 + lm];
#pragma unroll
                for (int r = 0; r < 4; ++r) {
                    float v = acc1[mt][nt][r] + bia;
                    v = 0.5f * v * (1.f + erff(v * 0.70710678118654752f));
                    h1s[(mw + mt * 16 + lk * 4 + r) * 136 + nw + nt * 16 + lm] = f2bf(v);
                }
            }
        __syncthreads();  // h1s ready
        // GEMM2 partial: h1 @ fc2w.T (K-chunk of 128)
#pragma unroll
        for (int kt = 0; kt < 4; ++kt) {
            v8s A0 = *(const v8s*)&h1s[(mw + lm) * 136 + kt * 32 + lk * 8];
            v8s A1 = *(const v8s*)&h1s[(mw + 16 + lm) * 136 + kt * 32 + lk * 8];
#pragma unroll
            for (int nt = 0; nt < 4; ++nt) {
                acc2[0][nt] = __builtin_amdgcn_mfma_f32_16x16x32_bf16(A0, B2[nt][kt], acc2[0][nt], 0, 0, 0);
                acc2[1][nt] = __builtin_amdgcn_mfma_f32_16x16x32_bf16(A1, B2[nt][kt], acc2[1][nt], 0, 0, 0);
            }
        }
    }

    // epilogue: + fc2b + xo residual, store channel-major fp32
#pragma unroll
    for (int mt = 0; mt < 2; ++mt)
#pragma unroll
        for (int nt = 0; nt < 4; ++nt) {
            int c = nw + nt * 16 + lm;
            float bia = fc2b[c];
            int tok0 = mw + mt * 16 + lk * 4;
            float4 o;
            o.x = acc2[mt][nt][0] + bia + xos[(tok0 + 0) * 132 + c];
            o.y = acc2[mt][nt][1] + bia + xos[(tok0 + 1) * 132 + c];
            o.z = acc2[mt][nt][2] + bia + xos[(tok0 + 2) * 132 + c];
            o.w = acc2[mt][nt][3] + bia + xos[(tok0 + 3) * 132 + c];
            *(float4*)&out[((b * C + c) * HH + h) * WW_ + w0 + tok0] = o;
        }
}

extern "C" void kernel_launch(void* const* d_in, const int* in_sizes, int n_in,
                              void* d_out, int out_size, void* d_ws, size_t ws_size,
                              hipStream_t stream) {
    const float* x    = (const float*)d_in[0];
    const float* kv   = (const float*)d_in[1];
    const float* n1g  = (const float*)d_in[2];
    const float* n1b  = (const float*)d_in[3];
    const float* qw   = (const float*)d_in[4];
    const float* qb   = (const float*)d_in[5];
    const float* kvw  = (const float*)d_in[6];
    const float* kvb  = (const float*)d_in[7];
    const float* rpb  = (const float*)d_in[8];
    const float* pw   = (const float*)d_in[9];
    const float* pb   = (const float*)d_in[10];
    const float* n2g  = (const float*)d_in[11];
    const float* n2b  = (const float*)d_in[12];
    const float* fc1w = (const float*)d_in[13];
    const float* fc1b = (const float*)d_in[14];
    const float* fc2w = (const float*)d_in[15];
    const float* fc2b = (const float*)d_in[16];
    float* out = (float*)d_out;

    char* ws = (char*)d_ws;
    unsigned short* qbuf = (unsigned short*)(ws);                 // 32 MB
    unsigned short* kbuf = (unsigned short*)(ws + 33554432);      // 32 MB
    unsigned short* vbuf = (unsigned short*)(ws + 67108864);      // 32 MB
    unsigned short* pbuf = (unsigned short*)(ws + 100663296);     // 32 MB
    // packed weights alias qbuf's region (dead after k_attn)
    unsigned short* W1p = (unsigned short*)(ws);                  // 128 KB
    unsigned short* W2p = (unsigned short*)(ws + 131072);         // 128 KB

    dim3 blkd(256);
    k_ln_q<<<dim3(2048), blkd, 0, stream>>>(x, n1g, n1b, qw, qb, qbuf);
    k_ln_kv<<<dim3(2048), blkd, 0, stream>>>(kv, n1g, n1b, kvw, kvb, kbuf, vbuf);
    k_attn<<<dim3(2048), blkd, 0, stream>>>(qbuf, kbuf, vbuf, rpb, pw, pb, pbuf);
    k_prep<<<dim3(64), blkd, 0, stream>>>(fc1w, fc2w, W1p, W2p);
    k_mlp2<<<dim3(2048), blkd, 0, stream>>>(x, pbuf, n2g, n2b, fc1b, fc2b, W1p, W2p, out);
}

// Round 7
// 478.988 us; speedup vs baseline: 3.1121x; 1.6289x over previous
//
#include <hip/hip_runtime.h>
#include <cstdint>

#define SHIFT_ 4

typedef short v8s __attribute__((ext_vector_type(8)));
typedef float v4f __attribute__((ext_vector_type(4)));

__device__ __forceinline__ float bf2f(unsigned short u) {
    unsigned v = ((unsigned)u) << 16;
    return __uint_as_float(v);
}
__device__ __forceinline__ unsigned short f2bf(float f) {
    unsigned u = __float_as_uint(f);
    return (unsigned short)((u + 0x7fffu + ((u >> 16) & 1u)) >> 16);
}
__device__ __forceinline__ void unpack8(uint4 u, float* dst, float sc) {
    dst[0] = bf2f((unsigned short)(u.x & 0xffffu)) * sc;
    dst[1] = bf2f((unsigned short)(u.x >> 16)) * sc;
    dst[2] = bf2f((unsigned short)(u.y & 0xffffu)) * sc;
    dst[3] = bf2f((unsigned short)(u.y >> 16)) * sc;
    dst[4] = bf2f((unsigned short)(u.z & 0xffffu)) * sc;
    dst[5] = bf2f((unsigned short)(u.z >> 16)) * sc;
    dst[6] = bf2f((unsigned short)(u.w & 0xffffu)) * sc;
    dst[7] = bf2f((unsigned short)(u.w >> 16)) * sc;
}

// ---------------- pack all weights frag-linear bf16 ----------------
// frag f: [0,32) qw | [32,96) kvw | [96,128) pw | [128,256) fc1w | [256,384) fc2w
// element: Wp[f*512 + l*8 + i] = W[(nt*16 + (l&15))*K + kt*32 + (l>>4)*8 + i]
__global__ __launch_bounds__(256) void k_prep2(const float* __restrict__ qw,
                                               const float* __restrict__ kvw,
                                               const float* __restrict__ pw,
                                               const float* __restrict__ fc1w,
                                               const float* __restrict__ fc2w,
                                               unsigned short* __restrict__ Wp) {
    int tid = blockIdx.x * 256 + threadIdx.x;  // 0..24575
    int f = tid >> 6, l = tid & 63;
    int lm = l & 15, lk = l >> 4;
    const float* src;
    int nt, kt, K;
    if (f < 32) {
        src = qw; nt = f >> 2; kt = f & 3; K = 128;
    } else if (f < 96) {
        src = kvw; int g = f - 32; nt = g >> 2; kt = g & 3; K = 128;
    } else if (f < 128) {
        src = pw; int g = f - 96; nt = g >> 2; kt = g & 3; K = 128;
    } else if (f < 256) {
        src = fc1w; int g = f - 128; nt = g >> 2; kt = g & 3; K = 128;
    } else {
        src = fc2w; int g = f - 256; nt = g >> 4; kt = g & 15; K = 512;
    }
    const float* s = &src[(nt * 16 + lm) * K + kt * 32 + lk * 8];
    unsigned short* d = &Wp[(size_t)tid * 8];
#pragma unroll
    for (int i = 0; i < 8; ++i) d[i] = f2bf(s[i]);
}

// ---------------- LN(x) (pre-rolled) + MFMA Q proj ----------------
__global__ __launch_bounds__(256) void k_ln_q2(const float* __restrict__ x,
                                               const float* __restrict__ g,
                                               const float* __restrict__ be,
                                               const float* __restrict__ qb,
                                               const unsigned short* __restrict__ qwp,
                                               unsigned short* __restrict__ qbuf) {
    __shared__ __align__(16) unsigned short x2s[64 * 136];
    __shared__ float red1[256], red2[256];
    __shared__ float mbuf[64], rbuf[64];
    __shared__ float gs[128], bsh[128];

    int t = threadIdx.x;
    int blk = blockIdx.x;
    int b = blk >> 10, rem = blk & 1023;
    int h = rem >> 2, w0 = (rem & 3) << 6;
    int hs = (h + SHIFT_) & 255;
    if (t < 128) { gs[t] = g[t]; bsh[t] = be[t]; }

    int j = t & 63, p = t >> 6;
    int wsrc = (w0 + j + SHIFT_) & 255;
    float v[32];
    float s1 = 0.f, s2 = 0.f;
#pragma unroll 8
    for (int k = 0; k < 32; ++k) {
        int c = p + 4 * k;
        float vv = x[((b * 128 + c) * 256 + hs) * 256 + wsrc];
        v[k] = vv; s1 += vv; s2 += vv * vv;
    }
    red1[t] = s1; red2[t] = s2;
    __syncthreads();
    if (t < 64) {
        float a = red1[t] + red1[64 + t] + red1[128 + t] + red1[192 + t];
        float q2 = red2[t] + red2[64 + t] + red2[128 + t] + red2[192 + t];
        float m = a * (1.f / 128.f);
        float var = q2 * (1.f / 128.f) - m * m;
        mbuf[t] = m; rbuf[t] = rsqrtf(var + 1e-5f);
    }
    __syncthreads();
    {
        float m = mbuf[j], r = rbuf[j];
#pragma unroll 8
        for (int k = 0; k < 32; ++k) {
            int c = p + 4 * k;
            x2s[j * 136 + c] = f2bf((v[k] - m) * r * gs[c] + bsh[c]);
        }
    }
    __syncthreads();

    int l = t & 63, wv = t >> 6;
    int lm = l & 15, lk = l >> 4;
    int mw = (wv >> 1) * 32, nwo = (wv & 1) * 64;
    v4f acc[2][4];
#pragma unroll
    for (int mt = 0; mt < 2; ++mt)
#pragma unroll
        for (int nt = 0; nt < 4; ++nt) acc[mt][nt] = (v4f){0.f, 0.f, 0.f, 0.f};
#pragma unroll
    for (int kt = 0; kt < 4; ++kt) {
        v8s A0 = *(const v8s*)&x2s[(mw + lm) * 136 + kt * 32 + lk * 8];
        v8s A1 = *(const v8s*)&x2s[(mw + 16 + lm) * 136 + kt * 32 + lk * 8];
#pragma unroll
        for (int nt = 0; nt < 4; ++nt) {
            v8s B = *(const v8s*)&qwp[(size_t)(((((wv & 1) * 4 + nt) * 4 + kt) * 64 + l)) * 8];
            acc[0][nt] = __builtin_amdgcn_mfma_f32_16x16x32_bf16(A0, B, acc[0][nt], 0, 0, 0);
            acc[1][nt] = __builtin_amdgcn_mfma_f32_16x16x32_bf16(A1, B, acc[1][nt], 0, 0, 0);
        }
    }
    size_t tokbase = ((size_t)(b * 256 + h)) * 256 + w0;
#pragma unroll
    for (int mt = 0; mt < 2; ++mt)
#pragma unroll
        for (int nt = 0; nt < 4; ++nt) {
            int c = nwo + nt * 16 + lm;
            float bia = qb[c];
#pragma unroll
            for (int r = 0; r < 4; ++r) {
                int tok = mw + mt * 16 + lk * 4 + r;
                qbuf[(tokbase + tok) * 128 + c] = f2bf((acc[mt][nt][r] + bia) * 0.17677669529663689f);
            }
        }
}

// ---------------- LN(kv) (pre-rolled) + MFMA K,V proj (V channel-major) ----------------
__global__ __launch_bounds__(256) void k_ln_kv2(const float* __restrict__ kv,
                                                const float* __restrict__ g,
                                                const float* __restrict__ be,
                                                const float* __restrict__ kvb,
                                                const unsigned short* __restrict__ kvwp,
                                                unsigned short* __restrict__ kbuf,
                                                unsigned short* __restrict__ vbufT) {
    __shared__ __align__(16) unsigned short x2s[64 * 136];
    __shared__ float red1[256], red2[256];
    __shared__ float mbuf[64], rbuf[64];
    __shared__ float gs[128], bsh[128];

    int t = threadIdx.x;
    int blk = blockIdx.x;
    int b = blk >> 10, rem = blk & 1023;
    int h = rem >> 2, w0 = (rem & 3) << 6;
    int hs = (h + SHIFT_) & 255;
    if (t < 128) { gs[t] = g[t]; bsh[t] = be[t]; }

    int j = t & 63, p = t >> 6;
    int wsrc = (w0 + j + SHIFT_) & 255;
    float v[32];
    float s1 = 0.f, s2 = 0.f;
#pragma unroll 8
    for (int k = 0; k < 32; ++k) {
        int c = p + 4 * k;
        float vv = kv[((b * 128 + c) * 256 + hs) * 256 + wsrc];
        v[k] = vv; s1 += vv; s2 += vv * vv;
    }
    red1[t] = s1; red2[t] = s2;
    __syncthreads();
    if (t < 64) {
        float a = red1[t] + red1[64 + t] + red1[128 + t] + red1[192 + t];
        float q2 = red2[t] + red2[64 + t] + red2[128 + t] + red2[192 + t];
        float m = a * (1.f / 128.f);
        float var = q2 * (1.f / 128.f) - m * m;
        mbuf[t] = m; rbuf[t] = rsqrtf(var + 1e-5f);
    }
    __syncthreads();
    {
        float m = mbuf[j], r = rbuf[j];
#pragma unroll 8
        for (int k = 0; k < 32; ++k) {
            int c = p + 4 * k;
            x2s[j * 136 + c] = f2bf((v[k] - m) * r * gs[c] + bsh[c]);
        }
    }
    __syncthreads();

    int l = t & 63, wv = t >> 6;
    int lm = l & 15, lk = l >> 4;
    int mw = (wv >> 1) * 32, nwo = (wv & 1) * 64;
    size_t tokbase = ((size_t)(b * 256 + h)) * 256 + w0;

    // ---- K ----
    {
        v4f acc[2][4];
#pragma unroll
        for (int mt = 0; mt < 2; ++mt)
#pragma unroll
            for (int nt = 0; nt < 4; ++nt) acc[mt][nt] = (v4f){0.f, 0.f, 0.f, 0.f};
#pragma unroll
        for (int kt = 0; kt < 4; ++kt) {
            v8s A0 = *(const v8s*)&x2s[(mw + lm) * 136 + kt * 32 + lk * 8];
            v8s A1 = *(const v8s*)&x2s[(mw + 16 + lm) * 136 + kt * 32 + lk * 8];
#pragma unroll
            for (int nt = 0; nt < 4; ++nt) {
                v8s B = *(const v8s*)&kvwp[(size_t)(((((wv & 1) * 4 + nt) * 4 + kt) * 64 + l)) * 8];
                acc[0][nt] = __builtin_amdgcn_mfma_f32_16x16x32_bf16(A0, B, acc[0][nt], 0, 0, 0);
                acc[1][nt] = __builtin_amdgcn_mfma_f32_16x16x32_bf16(A1, B, acc[1][nt], 0, 0, 0);
            }
        }
#pragma unroll
        for (int mt = 0; mt < 2; ++mt)
#pragma unroll
            for (int nt = 0; nt < 4; ++nt) {
                int c = nwo + nt * 16 + lm;
                float bia = kvb[c];
#pragma unroll
                for (int r = 0; r < 4; ++r) {
                    int tok = mw + mt * 16 + lk * 4 + r;
                    kbuf[(tokbase + tok) * 128 + c] = f2bf(acc[mt][nt][r] + bia);
                }
            }
    }
    // ---- V (channel-major out) ----
    {
        v4f acc[2][4];
#pragma unroll
        for (int mt = 0; mt < 2; ++mt)
#pragma unroll
            for (int nt = 0; nt < 4; ++nt) acc[mt][nt] = (v4f){0.f, 0.f, 0.f, 0.f};
#pragma unroll
        for (int kt = 0; kt < 4; ++kt) {
            v8s A0 = *(const v8s*)&x2s[(mw + lm) * 136 + kt * 32 + lk * 8];
            v8s A1 = *(const v8s*)&x2s[(mw + 16 + lm) * 136 + kt * 32 + lk * 8];
#pragma unroll
            for (int nt = 0; nt < 4; ++nt) {
                v8s B = *(const v8s*)&kvwp[(size_t)((((8 + (wv & 1) * 4 + nt) * 4 + kt) * 64 + l)) * 8];
                acc[0][nt] = __builtin_amdgcn_mfma_f32_16x16x32_bf16(A0, B, acc[0][nt], 0, 0, 0);
                acc[1][nt] = __builtin_amdgcn_mfma_f32_16x16x32_bf16(A1, B, acc[1][nt], 0, 0, 0);
            }
        }
#pragma unroll
        for (int mt = 0; mt < 2; ++mt)
#pragma unroll
            for (int nt = 0; nt < 4; ++nt) {
                int c = nwo + nt * 16 + lm;
                float bia = kvb[128 + c];
#pragma unroll
                for (int r = 0; r < 4; ++r) {
                    int tok = mw + mt * 16 + lk * 4 + r;
                    vbufT[(size_t)c * 131072 + tokbase + tok] = f2bf(acc[mt][nt][r] + bia);
                }
            }
    }
}

// ---------------- windowed attention: MFMA QK^T / PV / proj ----------------
__global__ __launch_bounds__(512) void k_attn2(const unsigned short* __restrict__ qbuf,
                                               const unsigned short* __restrict__ kbuf,
                                               const unsigned short* __restrict__ vbufT,
                                               const float* __restrict__ rpb,
                                               const unsigned short* __restrict__ pwp,
                                               const float* __restrict__ pb,
                                               unsigned short* __restrict__ pbuf) {
    __shared__ __align__(16) unsigned short q_lds[64 * 136];  // later reused as O
    __shared__ __align__(16) unsigned short k_lds[64 * 136];
    __shared__ __align__(16) unsigned short vt_lds[128 * 72];
    __shared__ __align__(16) unsigned short p_lds[4 * 64 * 72];
    __shared__ float rp[900];

    int t = threadIdx.x;
    int b = blockIdx.x >> 10;
    int wl = blockIdx.x & 1023;
    int wh = wl >> 5, wwid = wl & 31;

    for (int i = t; i < 900; i += 512) rp[i] = rpb[i];

    // stage Q,K (token-major rows of the window)
#pragma unroll
    for (int s = 0; s < 2; ++s) {
        int idx = s * 512 + t;
        int j = idx >> 4, part = idx & 15;
        int gt = (b * 256 + wh * 8 + (j >> 3)) * 256 + wwid * 8 + (j & 7);
        *(uint4*)&q_lds[j * 136 + part * 8] = *(const uint4*)&qbuf[(size_t)gt * 128 + part * 8];
        *(uint4*)&k_lds[j * 136 + part * 8] = *(const uint4*)&kbuf[(size_t)gt * 128 + part * 8];
    }
    // stage V^T [dim][key]
#pragma unroll
    for (int s = 0; s < 2; ++s) {
        int idx = s * 512 + t;
        int c = idx >> 3, rr = idx & 7;
        int gt = (b * 256 + wh * 8 + rr) * 256 + wwid * 8;
        *(uint4*)&vt_lds[c * 72 + rr * 8] = *(const uint4*)&vbufT[(size_t)c * 131072 + gt];
    }
    __syncthreads();

    int l = t & 63, wv = t >> 6;
    int lm = l & 15, lk = l >> 4;
    int h = wv >> 1, half = wv & 1;

    // QK^T (per head, wave covers 32 q rows)
    v4f s_[2][4];
#pragma unroll
    for (int mt = 0; mt < 2; ++mt)
#pragma unroll
        for (int nt = 0; nt < 4; ++nt) s_[mt][nt] = (v4f){0.f, 0.f, 0.f, 0.f};
    {
        v8s A0 = *(const v8s*)&q_lds[(half * 32 + lm) * 136 + h * 32 + lk * 8];
        v8s A1 = *(const v8s*)&q_lds[(half * 32 + 16 + lm) * 136 + h * 32 + lk * 8];
#pragma unroll
        for (int nt = 0; nt < 4; ++nt) {
            v8s B = *(const v8s*)&k_lds[(nt * 16 + lm) * 136 + h * 32 + lk * 8];
            s_[0][nt] = __builtin_amdgcn_mfma_f32_16x16x32_bf16(A0, B, s_[0][nt], 0, 0, 0);
            s_[1][nt] = __builtin_amdgcn_mfma_f32_16x16x32_bf16(A1, B, s_[1][nt], 0, 0, 0);
        }
    }

    // bias + mask + softmax (rows live on (lk,r), cols on lm)
    int kr_[4], kc_[4], regk_[4];
#pragma unroll
    for (int nt = 0; nt < 4; ++nt) {
        int kcol = nt * 16 + lm;
        kr_[nt] = kcol >> 3; kc_[nt] = kcol & 7;
        int hk = wh * 8 + kr_[nt], wk = wwid * 8 + kc_[nt];
        regk_[nt] = (hk < 248 ? 0 : (hk < 252 ? 1 : 2)) * 3 + (wk < 248 ? 0 : (wk < 252 ? 1 : 2));
    }
    float inv_[2][4];
#pragma unroll
    for (int mt = 0; mt < 2; ++mt) {
#pragma unroll
        for (int r = 0; r < 4; ++r) {
            int q = half * 32 + mt * 16 + lk * 4 + r;
            int qr = q >> 3, qc = q & 7;
            int hq = wh * 8 + qr, wq = wwid * 8 + qc;
            int regq = (hq < 248 ? 0 : (hq < 252 ? 1 : 2)) * 3 + (wq < 248 ? 0 : (wq < 252 ? 1 : 2));
            float sv[4];
#pragma unroll
            for (int nt = 0; nt < 4; ++nt) {
                float s = s_[mt][nt][r];
                s += rp[((qr - kr_[nt] + 7) * 15 + (qc - kc_[nt] + 7)) * 4 + h];
                if (regk_[nt] != regq) s -= 100.f;
                sv[nt] = s;
            }
            float mx = fmaxf(fmaxf(sv[0], sv[1]), fmaxf(sv[2], sv[3]));
            mx = fmaxf(mx, __shfl_xor(mx, 1));
            mx = fmaxf(mx, __shfl_xor(mx, 2));
            mx = fmaxf(mx, __shfl_xor(mx, 4));
            mx = fmaxf(mx, __shfl_xor(mx, 8));
            float e0 = __expf(sv[0] - mx), e1 = __expf(sv[1] - mx);
            float e2 = __expf(sv[2] - mx), e3 = __expf(sv[3] - mx);
            float sum = (e0 + e1) + (e2 + e3);
            sum += __shfl_xor(sum, 1);
            sum += __shfl_xor(sum, 2);
            sum += __shfl_xor(sum, 4);
            sum += __shfl_xor(sum, 8);
            inv_[mt][r] = 1.f / sum;
            unsigned short* pr = &p_lds[(h * 64 + q) * 72];
            pr[0 * 16 + lm] = f2bf(e0);
            pr[1 * 16 + lm] = f2bf(e1);
            pr[2 * 16 + lm] = f2bf(e2);
            pr[3 * 16 + lm] = f2bf(e3);
        }
    }

    // PV (wave-local P rows; no barrier needed)
    v4f o_[2][2];
#pragma unroll
    for (int mt = 0; mt < 2; ++mt)
#pragma unroll
        for (int nt = 0; nt < 2; ++nt) o_[mt][nt] = (v4f){0.f, 0.f, 0.f, 0.f};
#pragma unroll
    for (int kt = 0; kt < 2; ++kt) {
        v8s Pa0 = *(const v8s*)&p_lds[(h * 64 + half * 32 + lm) * 72 + kt * 32 + lk * 8];
        v8s Pa1 = *(const v8s*)&p_lds[(h * 64 + half * 32 + 16 + lm) * 72 + kt * 32 + lk * 8];
        v8s Vb0 = *(const v8s*)&vt_lds[(h * 32 + lm) * 72 + kt * 32 + lk * 8];
        v8s Vb1 = *(const v8s*)&vt_lds[(h * 32 + 16 + lm) * 72 + kt * 32 + lk * 8];
        o_[0][0] = __builtin_amdgcn_mfma_f32_16x16x32_bf16(Pa0, Vb0, o_[0][0], 0, 0, 0);
        o_[0][1] = __builtin_amdgcn_mfma_f32_16x16x32_bf16(Pa0, Vb1, o_[0][1], 0, 0, 0);
        o_[1][0] = __builtin_amdgcn_mfma_f32_16x16x32_bf16(Pa1, Vb0, o_[1][0], 0, 0, 0);
        o_[1][1] = __builtin_amdgcn_mfma_f32_16x16x32_bf16(Pa1, Vb1, o_[1][1], 0, 0, 0);
    }
    // scale by 1/sum, write O into q_lds region (cells are wave-local: same (rows,cols) this wave read as Q)
#pragma unroll
    for (int mt = 0; mt < 2; ++mt)
#pragma unroll
        for (int nt = 0; nt < 2; ++nt)
#pragma unroll
            for (int r = 0; r < 4; ++r) {
                int tok = half * 32 + mt * 16 + lk * 4 + r;
                q_lds[tok * 136 + h * 32 + nt * 16 + lm] = f2bf(o_[mt][nt][r] * inv_[mt][r]);
            }
    __syncthreads();

    // proj: out = O @ pw.T + pb ; un-roll and store bf16 token-major
    int mw = (wv & 3) * 16, nwo = (wv >> 2) * 64;
    v4f pacc[4];
#pragma unroll
    for (int nt = 0; nt < 4; ++nt) pacc[nt] = (v4f){0.f, 0.f, 0.f, 0.f};
#pragma unroll
    for (int kt = 0; kt < 4; ++kt) {
        v8s Ao = *(const v8s*)&q_lds[(mw + lm) * 136 + kt * 32 + lk * 8];
#pragma unroll
        for (int nt = 0; nt < 4; ++nt) {
            v8s B = *(const v8s*)&pwp[(size_t)(((((wv >> 2) * 4 + nt) * 4 + kt) * 64 + l)) * 8];
            pacc[nt] = __builtin_amdgcn_mfma_f32_16x16x32_bf16(Ao, B, pacc[nt], 0, 0, 0);
        }
    }
#pragma unroll
    for (int nt = 0; nt < 4; ++nt) {
        int c = nwo + nt * 16 + lm;
        float bia = pb[c];
#pragma unroll
        for (int r = 0; r < 4; ++r) {
            int tok = mw + lk * 4 + r;
            int rw = tok >> 3, cw = tok & 7;
            int hu = (wh * 8 + rw + SHIFT_) & 255;
            int wu = (wwid * 8 + cw + SHIFT_) & 255;
            pbuf[((size_t)(b * 256 + hu) * 256 + wu) * 128 + c] = f2bf(pacc[nt][r] + bia);
        }
    }
}

// ---------------- residual + LN2 + MFMA MLP + residual ----------------
__global__ __launch_bounds__(256, 2) void k_mlp2(const float* __restrict__ x,
                                                 const unsigned short* __restrict__ pbuf,
                                                 const float* __restrict__ g2,
                                                 const float* __restrict__ b2,
                                                 const float* __restrict__ fc1b,
                                                 const float* __restrict__ fc2b,
                                                 const unsigned short* __restrict__ W1p,
                                                 const unsigned short* __restrict__ W2p,
                                                 float* __restrict__ out) {
    __shared__ __align__(16) float xos[64 * 132];
    __shared__ __align__(16) unsigned short x2s[64 * 136];
    __shared__ __align__(16) unsigned short h1s[64 * 136];
    __shared__ float red1[256], red2[256];
    __shared__ float mbuf[64], rbuf[64];
    __shared__ float gs[128], bs[128];

    int t = threadIdx.x;
    int blk = blockIdx.x;
    int b = blk >> 10;
    int rem = blk & 1023;
    int h = rem >> 2;
    int w0 = (rem & 3) << 6;
    int tokbase = (b * 256 + h) * 256 + w0;

    if (t < 128) { gs[t] = g2[t]; bs[t] = b2[t]; }

    for (int s = 0; s < 4; ++s) {
        int flat = s * 256 + t;
        int j = flat >> 4, c8 = flat & 15;
        uint4 u = ((const uint4*)&pbuf[(size_t)(tokbase + j) * 128])[c8];
        unpack8(u, &xos[j * 132 + c8 * 8], 1.f);
    }
    __syncthreads();

    int j = t & 63, p = t >> 6;
    float s1 = 0.f, s2 = 0.f;
#pragma unroll 8
    for (int k = 0; k < 32; ++k) {
        int c = p + 4 * k;
        float v = xos[j * 132 + c] + x[((b * 128 + c) * 256 + h) * 256 + w0 + j];
        xos[j * 132 + c] = v;
        s1 += v; s2 += v * v;
    }
    red1[t] = s1; red2[t] = s2;
    __syncthreads();
    if (t < 64) {
        float a = red1[t] + red1[64 + t] + red1[128 + t] + red1[192 + t];
        float q2 = red2[t] + red2[64 + t] + red2[128 + t] + red2[192 + t];
        float m = a * (1.f / 128.f);
        float var = q2 * (1.f / 128.f) - m * m;
        mbuf[t] = m; rbuf[t] = rsqrtf(var + 1e-5f);
    }
    __syncthreads();
    {
        float m = mbuf[j], r = rbuf[j];
#pragma unroll 8
        for (int k = 0; k < 32; ++k) {
            int c = p + 4 * k;
            x2s[j * 136 + c] = f2bf((xos[j * 132 + c] - m) * r * gs[c] + bs[c]);
        }
    }
    __syncthreads();

    int l = t & 63, w = t >> 6;
    int mw = (w >> 1) * 32;
    int nw = (w & 1) * 64;
    int lm = l & 15, lk = l >> 4;

    v4f acc2[2][4];
#pragma unroll
    for (int mt = 0; mt < 2; ++mt)
#pragma unroll
        for (int nt = 0; nt < 4; ++nt) acc2[mt][nt] = (v4f){0.f, 0.f, 0.f, 0.f};

    for (int ch = 0; ch < 4; ++ch) {
        v8s B1[4][4], B2[4][4];
#pragma unroll
        for (int nt = 0; nt < 4; ++nt)
#pragma unroll
            for (int kt = 0; kt < 4; ++kt)
                B1[nt][kt] = *(const v8s*)&W1p[(size_t)((((ch * 8 + (w & 1) * 4 + nt) * 4 + kt) * 64 + l)) * 8];
#pragma unroll
        for (int nt = 0; nt < 4; ++nt)
#pragma unroll
            for (int kt = 0; kt < 4; ++kt)
                B2[nt][kt] = *(const v8s*)&W2p[(size_t)(((((w & 1) * 4 + nt) * 16 + ch * 4 + kt) * 64 + l)) * 8];

        v4f acc1[2][4];
#pragma unroll
        for (int mt = 0; mt < 2; ++mt)
#pragma unroll
            for (int nt = 0; nt < 4; ++nt) acc1[mt][nt] = (v4f){0.f, 0.f, 0.f, 0.f};
#pragma unroll
        for (int kt = 0; kt < 4; ++kt) {
            v8s A0 = *(const v8s*)&x2s[(mw + lm) * 136 + kt * 32 + lk * 8];
            v8s A1 = *(const v8s*)&x2s[(mw + 16 + lm) * 136 + kt * 32 + lk * 8];
#pragma unroll
            for (int nt = 0; nt < 4; ++nt) {
                acc1[0][nt] = __builtin_amdgcn_mfma_f32_16x16x32_bf16(A0, B1[nt][kt], acc1[0][nt], 0, 0, 0);
                acc1[1][nt] = __builtin_amdgcn_mfma_f32_16x16x32_bf16(A1, B1[nt][kt], acc1[1][nt], 0, 0, 0);
            }
        }
        __syncthreads();
#pragma unroll
        for (int mt = 0; mt < 2; ++mt)
#pragma unroll
            for (int nt = 0; nt < 4; ++nt) {
                float bia = fc1b[ch * 128 + nw + nt * 16 + lm];
#pragma unroll
                for (int r = 0; r < 4; ++r) {
                    float v = acc1[mt][nt][r] + bia;
                    v = 0.5f * v * (1.f + erff(v * 0.70710678118654752f));
                    h1s[(mw + mt * 16 + lk * 4 + r) * 136 + nw + nt * 16 + lm] = f2bf(v);
                }
            }
        __syncthreads();
#pragma unroll
        for (int kt = 0; kt < 4; ++kt) {
            v8s A0 = *(const v8s*)&h1s[(mw + lm) * 136 + kt * 32 + lk * 8];
            v8s A1 = *(const v8s*)&h1s[(mw + 16 + lm) * 136 + kt * 32 + lk * 8];
#pragma unroll
            for (int nt = 0; nt < 4; ++nt) {
                acc2[0][nt] = __builtin_amdgcn_mfma_f32_16x16x32_bf16(A0, B2[nt][kt], acc2[0][nt], 0, 0, 0);
                acc2[1][nt] = __builtin_amdgcn_mfma_f32_16x16x32_bf16(A1, B2[nt][kt], acc2[1][nt], 0, 0, 0);
            }
        }
    }

#pragma unroll
    for (int mt = 0; mt < 2; ++mt)
#pragma unroll
        for (int nt = 0; nt < 4; ++nt) {
            int c = nw + nt * 16 + lm;
            float bia = fc2b[c];
            int tok0 = mw + mt * 16 + lk * 4;
            float4 o;
            o.x = acc2[mt][nt][0] + bia + xos[(tok0 + 0) * 132 + c];
            o.y = acc2[mt][nt][1] + bia + xos[(tok0 + 1) * 132 + c];
            o.z = acc2[mt][nt][2] + bia + xos[(tok0 + 2) * 132 + c];
            o.w = acc2[mt][nt][3] + bia + xos[(tok0 + 3) * 132 + c];
            *(float4*)&out[((size_t)(b * 128 + c) * 256 + h) * 256 + w0 + tok0] = o;
        }
}

extern "C" void kernel_launch(void* const* d_in, const int* in_sizes, int n_in,
                              void* d_out, int out_size, void* d_ws, size_t ws_size,
                              hipStream_t stream) {
    const float* x    = (const float*)d_in[0];
    const float* kv   = (const float*)d_in[1];
    const float* n1g  = (const float*)d_in[2];
    const float* n1b  = (const float*)d_in[3];
    const float* qw   = (const float*)d_in[4];
    const float* qb   = (const float*)d_in[5];
    const float* kvw  = (const float*)d_in[6];
    const float* kvb  = (const float*)d_in[7];
    const float* rpb  = (const float*)d_in[8];
    const float* pw   = (const float*)d_in[9];
    const float* pb   = (const float*)d_in[10];
    const float* n2g  = (const float*)d_in[11];
    const float* n2b  = (const float*)d_in[12];
    const float* fc1w = (const float*)d_in[13];
    const float* fc1b = (const float*)d_in[14];
    const float* fc2w = (const float*)d_in[15];
    const float* fc2b = (const float*)d_in[16];
    float* out = (float*)d_out;

    char* ws = (char*)d_ws;
    unsigned short* qbuf  = (unsigned short*)(ws);                 // 32 MB
    unsigned short* kbuf  = (unsigned short*)(ws + 33554432);      // 32 MB
    unsigned short* vbufT = (unsigned short*)(ws + 67108864);      // 32 MB, [c][tok]
    unsigned short* pbuf  = (unsigned short*)(ws + 100663296);     // 32 MB
    unsigned short* Wpack = (unsigned short*)(ws + 134217728);     // 384 KB packed weights
    // sections (shorts): qwp@0, kvwp@16384, pwp@49152, W1p@65536, W2p@131072

    k_prep2<<<dim3(96), dim3(256), 0, stream>>>(qw, kvw, pw, fc1w, fc2w, Wpack);
    k_ln_q2<<<dim3(2048), dim3(256), 0, stream>>>(x, n1g, n1b, qb, Wpack, qbuf);
    k_ln_kv2<<<dim3(2048), dim3(256), 0, stream>>>(kv, n1g, n1b, kvb, Wpack + 16384, kbuf, vbufT);
    k_attn2<<<dim3(2048), dim3(512), 0, stream>>>(qbuf, kbuf, vbufT, rpb, Wpack + 49152, pb, pbuf);
    k_mlp2<<<dim3(2048), dim3(256), 0, stream>>>(x, pbuf, n2g, n2b, fc1b, fc2b,
                                                 Wpack + 65536, Wpack + 131072, out);
}